// Round 1
// baseline (2888.397 us; speedup 1.0000x reference)
//
#include <hip/hip_runtime.h>

// 2-layer LSTM (B=256, T=1024, H=256, IN=1), inference; outputs h_n[2,256,256], c_n[2,256,256] f32.
//
// Decomposition: 16 clusters (16 batch rows each) x 16 WGs (each owns 16 j-indices x 4 gates).
// Weights live in VGPRs as MFMA B-fragments. Both layers computed in one skewed step:
// combined step s: layer0 state s (from h0[s-1]) and layer1 state s-1 (inputs: y0[t=s-2]=h0[s-1], h1[s-2]).
// Cross-WG h exchange via agent-scope relaxed atomics (device coherence point, no fences needed)
// gated by per-WG sequence flags; h buffers double-buffered by step parity.

#define T_STEPS 1024u

typedef __attribute__((ext_vector_type(8))) short bf16x8;
typedef __attribute__((ext_vector_type(4))) float f32x4;

__device__ __forceinline__ unsigned short f2bf(float f) {
  unsigned u = __float_as_uint(f);
  u += 0x7FFFu + ((u >> 16) & 1u);   // RNE
  return (unsigned short)(u >> 16);
}

__device__ __forceinline__ float sigm(float x) {
  return 1.0f / (1.0f + __expf(-x));
}

__device__ __forceinline__ float tanh_f(float x) {
  float xc = fminf(fmaxf(x, -15.0f), 15.0f);
  float e = __expf(2.0f * xc);
  return (e - 1.0f) / (e + 1.0f);
}

__global__ __launch_bounds__(256, 1) void lstm2_kernel(
    const float* __restrict__ x,     // [256][1024]
    const float* __restrict__ Wih0,  // [1024][1]
    const float* __restrict__ Whh0,  // [1024][256]
    const float* __restrict__ bih0, const float* __restrict__ bhh0,
    const float* __restrict__ Wih1,  // [1024][256]
    const float* __restrict__ Whh1,  // [1024][256]
    const float* __restrict__ bih1, const float* __restrict__ bhh1,
    float* __restrict__ out,         // [4][256][256]: h_n(2) then c_n(2)
    unsigned* __restrict__ ws)       // flags @0 (256 u32), hbuf0 @4096B, hbuf1 @4096B+256KB
{
  const int bid  = blockIdx.x;
  const int c    = bid & 15;   // cluster (batch group)
  const int iw   = bid >> 4;   // WG index within cluster (j-slice)
  const int tid  = threadIdx.x;
  const int lane = tid & 63;
  const int g    = tid >> 6;   // wave id == gate id (i,f,g,o)
  const int rowE = tid >> 4;   // elementwise: local batch row
  const int jlE  = tid & 15;   // elementwise: local j

  unsigned* flagF = ws + c * 16;                                   // per-cluster 16 flags
  unsigned short* hb0 = (unsigned short*)((char*)ws + 4096) + (size_t)c * 8192;   // [2][16][256]
  unsigned short* hb1 = (unsigned short*)((char*)ws + 4096) + 131072 + (size_t)c * 8192;

  // ---- preload weight B-fragments (bf16) into registers: 3 matrices x 8 k-chunks
  bf16x8 w0[8], wi1[8], wh1[8];
  {
    const int bcol = (g << 8) + (iw << 4) + (lane & 15);  // global gate column
    const int kb   = (lane >> 4) << 3;
#pragma unroll
    for (int kk = 0; kk < 8; ++kk) {
      const int k0 = kk * 32 + kb;
      const float* p0 = Whh0 + (size_t)bcol * 256 + k0;
      const float* p1 = Wih1 + (size_t)bcol * 256 + k0;
      const float* p2 = Whh1 + (size_t)bcol * 256 + k0;
      bf16x8 a, b, cc;
#pragma unroll
      for (int e = 0; e < 8; ++e) {
        a[e]  = (short)f2bf(p0[e]);
        b[e]  = (short)f2bf(p1[e]);
        cc[e] = (short)f2bf(p2[e]);
      }
      w0[kk] = a; wi1[kk] = b; wh1[kk] = cc;
    }
  }

  // ---- per-thread elementwise constants (bias sums, layer0 input weights)
  float wx[4], bs0[4], bs1[4];
#pragma unroll
  for (int q = 0; q < 4; ++q) {
    const int col = (q << 8) + (iw << 4) + jlE;
    wx[q]  = Wih0[col];
    bs0[q] = bih0[col] + bhh0[col];
    bs1[q] = bih1[col] + bhh1[col];
  }

  __shared__ __align__(16) unsigned short A0[16][264];  // h0 state s-1 (16 rows x 256, +8 pad)
  __shared__ __align__(16) unsigned short A1[16][264];  // h1 state s-2
  __shared__ float gl[2][4][16][16];                    // gate tiles: [layer][gate][row][j]

  const float* xrow = x + (size_t)((c << 4) + rowE) * T_STEPS;

  float c0 = 0.f, h0f = 0.f, c1 = 0.f, h1f = 0.f;
  bool dead = false;

  const int srow = tid >> 4;       // staging row
  const int sseg = tid & 15;       // staging 16-ushort segment
  const unsigned hoff = (unsigned)((iw << 4) + jlE);

  for (unsigned s = 1; s <= T_STEPS + 1u; ++s) {
    // 1) wait until whole cluster has published state s-1
    if (!dead) {
      const unsigned idx = (unsigned)tid & 15u;
      int it = 0;
      while (true) {
        unsigned v = __hip_atomic_load(&flagF[idx], __ATOMIC_RELAXED, __HIP_MEMORY_SCOPE_AGENT);
        if (__all((int)(v >= s - 1u))) break;
        if (++it > (1 << 21)) { dead = true; break; }   // sticky bailout (avoid hang on bug)
        __builtin_amdgcn_s_sleep(1);
      }
    }
    asm volatile("" ::: "memory");

    // 2) stage h0[s-1] and h1[s-2] tiles into LDS (agent-scope loads bypass L1)
    {
      const unsigned p0 = (s - 1u) & 1u;
      const unsigned p1 = (s - 2u) & 1u;  // s=1 -> parity 1 (zero-initialized)
      const unsigned short* h0src = hb0 + p0 * 4096 + srow * 256 + sseg * 16;
      const unsigned short* h1src = hb1 + p1 * 4096 + srow * 256 + sseg * 16;
      unsigned long long q0[4], q1[4];
#pragma unroll
      for (int e = 0; e < 4; ++e) {
        q0[e] = __hip_atomic_load((const unsigned long long*)(h0src + e * 4),
                                  __ATOMIC_RELAXED, __HIP_MEMORY_SCOPE_AGENT);
        q1[e] = __hip_atomic_load((const unsigned long long*)(h1src + e * 4),
                                  __ATOMIC_RELAXED, __HIP_MEMORY_SCOPE_AGENT);
      }
#pragma unroll
      for (int e = 0; e < 4; ++e) {
        *(unsigned long long*)&A0[srow][sseg * 16 + e * 4] = q0[e];
        *(unsigned long long*)&A1[srow][sseg * 16 + e * 4] = q1[e];
      }
    }
    __syncthreads();

    // 3) MFMA: acc0 = h0[s-1] @ Whh0^T ; acc1 = h0[s-1] @ Wih1^T + h1[s-2] @ Whh1^T
    f32x4 acc0 = {0.f, 0.f, 0.f, 0.f};
    f32x4 acc1 = {0.f, 0.f, 0.f, 0.f};
    {
      const int ar = lane & 15;
      const int kb = (lane >> 4) << 3;
      const unsigned short* a0p = &A0[ar][kb];
      const unsigned short* a1p = &A1[ar][kb];
#pragma unroll
      for (int kk = 0; kk < 8; ++kk) {
        bf16x8 af = *(const bf16x8*)(a0p + kk * 32);
        acc0 = __builtin_amdgcn_mfma_f32_16x16x32_bf16(af, w0[kk], acc0, 0, 0, 0);
        acc1 = __builtin_amdgcn_mfma_f32_16x16x32_bf16(af, wi1[kk], acc1, 0, 0, 0);
      }
#pragma unroll
      for (int kk = 0; kk < 8; ++kk) {
        bf16x8 af = *(const bf16x8*)(a1p + kk * 32);
        acc1 = __builtin_amdgcn_mfma_f32_16x16x32_bf16(af, wh1[kk], acc1, 0, 0, 0);
      }
    }
    {
      const int dr = (lane >> 4) << 2;
      const int dc = lane & 15;
#pragma unroll
      for (int r = 0; r < 4; ++r) {
        gl[0][g][dr + r][dc] = acc0[r];
        gl[1][g][dr + r][dc] = acc1[r];
      }
    }
    __syncthreads();

    // 4) elementwise cell updates (f32 state), publish bf16 h via packed u32 agent atomics
    unsigned hp0 = 0;
    if (s <= T_STEPS) {
      const float xv = xrow[s - 1u];
      const float pi = gl[0][0][rowE][jlE] + xv * wx[0] + bs0[0];
      const float pf = gl[0][1][rowE][jlE] + xv * wx[1] + bs0[1];
      const float pg = gl[0][2][rowE][jlE] + xv * wx[2] + bs0[2];
      const float po = gl[0][3][rowE][jlE] + xv * wx[3] + bs0[3];
      const float ig = sigm(pi), fg = sigm(pf), gv = tanh_f(pg), og = sigm(po);
      c0  = fg * c0 + ig * gv;
      h0f = og * tanh_f(c0);
      hp0 = (unsigned)f2bf(h0f);
    }
    unsigned op0 = (unsigned)__shfl_xor((int)hp0, 1);
    if (s <= T_STEPS && ((jlE & 1) == 0)) {
      unsigned val = hp0 | (op0 << 16);
      unsigned short* dst = hb0 + (s & 1u) * 4096 + rowE * 256 + hoff;
      __hip_atomic_store((unsigned*)dst, val, __ATOMIC_RELAXED, __HIP_MEMORY_SCOPE_AGENT);
    }

    unsigned hp1 = 0;
    if (s >= 2u) {
      const float pi = gl[1][0][rowE][jlE] + bs1[0];
      const float pf = gl[1][1][rowE][jlE] + bs1[1];
      const float pg = gl[1][2][rowE][jlE] + bs1[2];
      const float po = gl[1][3][rowE][jlE] + bs1[3];
      const float ig = sigm(pi), fg = sigm(pf), gv = tanh_f(pg), og = sigm(po);
      c1  = fg * c1 + ig * gv;
      h1f = og * tanh_f(c1);
      hp1 = (unsigned)f2bf(h1f);
    }
    unsigned op1 = (unsigned)__shfl_xor((int)hp1, 1);
    if (s >= 2u && ((jlE & 1) == 0)) {
      unsigned val = hp1 | (op1 << 16);
      unsigned short* dst = hb1 + ((s - 1u) & 1u) * 4096 + rowE * 256 + hoff;
      __hip_atomic_store((unsigned*)dst, val, __ATOMIC_RELAXED, __HIP_MEMORY_SCOPE_AGENT);
    }

    __syncthreads();   // compiler drains vmcnt per wave before s_barrier => stores complete
    if (tid == 0) {
      __hip_atomic_store(&flagF[iw], s, __ATOMIC_RELAXED, __HIP_MEMORY_SCOPE_AGENT);
    }
  }

  // ---- epilogue: final states, full f32
  {
    const int b  = (c << 4) + rowE;
    const int jg = (iw << 4) + jlE;
    const size_t o = (size_t)b * 256 + jg;
    out[o]                  = h0f;  // h_n layer 0
    out[65536 + o]          = h1f;  // h_n layer 1
    out[131072 + o]         = c0;   // c_n layer 0
    out[131072 + 65536 + o] = c1;   // c_n layer 1
  }
}

extern "C" void kernel_launch(void* const* d_in, const int* in_sizes, int n_in,
                              void* d_out, int out_size, void* d_ws, size_t ws_size,
                              hipStream_t stream) {
  const float* x    = (const float*)d_in[0];
  const float* Wih0 = (const float*)d_in[1];
  const float* Whh0 = (const float*)d_in[2];
  const float* bih0 = (const float*)d_in[3];
  const float* bhh0 = (const float*)d_in[4];
  const float* Wih1 = (const float*)d_in[5];
  const float* Whh1 = (const float*)d_in[6];
  const float* bih1 = (const float*)d_in[7];
  const float* bhh1 = (const float*)d_in[8];

  // zero flags (256 u32 @0) + both h double-buffers (2 x 256KB @4096B)
  hipMemsetAsync(d_ws, 0, 528384, stream);

  lstm2_kernel<<<256, 256, 0, stream>>>(x, Wih0, Whh0, bih0, bhh0,
                                        Wih1, Whh1, bih1, bhh1,
                                        (float*)d_out, (unsigned*)d_ws);
}